// Round 8
// baseline (294.838 us; speedup 1.0000x reference)
//
#include <hip/hip_runtime.h>
#include <hip/hip_bf16.h>
#include <hip/hip_cooperative_groups.h>

namespace cg = cooperative_groups;

typedef __attribute__((ext_vector_type(8))) short short8;
typedef __attribute__((ext_vector_type(4))) float f32x4;
typedef unsigned short u16;
typedef unsigned int u32;

constexpr int CB = 4, CN = 2048, CF = 128, CD = 64, CH = 4;
constexpr int IT = 32;   // i-rows per block

__device__ inline u32 fmap(float f) {
    u32 b = __float_as_uint(f);
    return b ^ ((u32)(((int)b) >> 31) | 0x80000000u);
}
__device__ inline float funmap(u32 u) {
    u32 b = (u & 0x80000000u) ? (u ^ 0x80000000u) : ~u;
    return __uint_as_float(b);
}
__device__ inline u16 bf16bits(float v) {
    __hip_bfloat16 b = __float2bfloat16(v);
    return *reinterpret_cast<u16*>(&b);
}

// ---------------------------------------------------------------------------
// Single cooperative kernel. 256 blocks x 1024 threads, 1 block/CU.
// Block <-> (b, 32-row i-tile) via XCD swizzle: each XCD owns exactly one b,
// so phase-1 writes (hT/s/E of that b) are consumed from the same XCD's L2
// in phase 2 (no kernel-boundary cache flush in between).
// ---------------------------------------------------------------------------
__global__ __launch_bounds__(1024) void fused_k(
    const float* __restrict__ X, const int* __restrict__ A,
    const float* __restrict__ W, const float* __restrict__ AK,
    float* __restrict__ out,
    float* __restrict__ s_ws, float* __restrict__ e_ws,
    u32* __restrict__ smax_u, u32* __restrict__ mask_ws,
    u16* __restrict__ hT, u16* __restrict__ WThi, u16* __restrict__ WTlo) {

    __shared__ alignas(16) float e_sl[CH][CN];       // 32 KB
    __shared__ u32 m_lds[IT][65];                    // 8.3 KB
    __shared__ alignas(16) float cbuf[CH][2][IT][68];// 69.6 KB (aliased by tr)
    __shared__ float lbuf[CH][4][IT];                // 2 KB
    float (*tr)[CD][17] = reinterpret_cast<float (*)[CD][17]>(&cbuf[0][0][0][0]);

    cg::grid_group gg = cg::this_grid();
    int bi = blockIdx.x, t = threadIdx.x;
    int w = t >> 6, l = t & 63;
    int xcd = bi & 7, pos = bi >> 3;
    int b = xcd >> 1;                       // XCD owns one b
    int i0 = ((xcd & 1) * 32 + pos) * IT;   // this block's 32 rows
    int row_l = l & 15, jg = l >> 4;

    // ================= phase 0: mask pack + WT convert + smax init ========
#pragma unroll
    for (int it2 = 0; it2 < 16; ++it2) {
        int idx = it2 * 1024 + t;                  // 8 rows x 2048 cols
        int r = bi * 8 + (idx >> 11), ccol = idx & 2047;
        unsigned long long mk = __ballot(A[(size_t)r * CN + ccol] > 0);
        if (l == 0) {
            mask_ws[r * 64 + (ccol >> 5)] = (u32)mk;
            mask_ws[r * 64 + (ccol >> 5) + 1] = (u32)(mk >> 32);
        }
    }
    if (t < 128) {
        int idx = bi * 128 + t;                    // H*F*D = 32768 total
        int h = idx >> 13, f = (idx >> 6) & 127, d = idx & 63;
        float v = W[idx];
        __hip_bfloat16 bh = __float2bfloat16(v);
        int o = (h * CD + d) * CF + f;
        WThi[o] = *reinterpret_cast<u16*>(&bh);
        WTlo[o] = bf16bits(v - __bfloat162float(bh));
    }
    if (bi == 0 && t < CH * CB) smax_u[t] = 0u;
    __threadfence();
    gg.sync();

    // ================= phase 1: projection (waves 0-7) ====================
    if (w < 8) {
        int h = w & 3, tt = w >> 2;
        int n0 = i0 + tt * 16;
        const float* xrow = X + ((size_t)b * CN + n0 + row_l) * CF + jg * 8;
        const u16* whi = WThi + (size_t)h * CD * CF;
        const u16* wlo = WTlo + (size_t)h * CD * CF;

        float4 xa[4], xb[4];
#pragma unroll
        for (int kk = 0; kk < 4; ++kk) {
            xa[kk] = *reinterpret_cast<const float4*>(xrow + kk * 32);
            xb[kk] = *reinterpret_cast<const float4*>(xrow + kk * 32 + 4);
        }

        short8 wh0[4], wl0[4], wh1[4], wl1[4];
#define LOADW(BH, BL, KK)                                                 \
        _Pragma("unroll") for (int dt = 0; dt < 4; ++dt) {                \
            int off = (dt * 16 + row_l) * CF + (KK) * 32 + jg * 8;        \
            BH[dt] = *reinterpret_cast<const short8*>(whi + off);         \
            BL[dt] = *reinterpret_cast<const short8*>(wlo + off);         \
        }
        LOADW(wh0, wl0, 0);

        f32x4 c[4];
        f32x4 zero = {0.f, 0.f, 0.f, 0.f};
#pragma unroll
        for (int dt = 0; dt < 4; ++dt) c[dt] = zero;

#define PROJ_STEP(KK, CURH, CURL, NXTH, NXTL, KN)                         \
        do {                                                              \
            if ((KN) != (KK)) { LOADW(NXTH, NXTL, KN); }                  \
            float xv[8] = {xa[KK].x, xa[KK].y, xa[KK].z, xa[KK].w,        \
                           xb[KK].x, xb[KK].y, xb[KK].z, xb[KK].w};       \
            short8 ahi, alo;                                              \
            _Pragma("unroll") for (int e = 0; e < 8; ++e) {               \
                __hip_bfloat16 bh_ = __float2bfloat16(xv[e]);             \
                ahi[e] = (short)*reinterpret_cast<u16*>(&bh_);            \
                alo[e] = (short)bf16bits(xv[e] - __bfloat162float(bh_));  \
            }                                                             \
            _Pragma("unroll") for (int dt = 0; dt < 4; ++dt) {            \
                c[dt] = __builtin_amdgcn_mfma_f32_16x16x32_bf16(ahi, CURH[dt], c[dt], 0, 0, 0); \
                c[dt] = __builtin_amdgcn_mfma_f32_16x16x32_bf16(ahi, CURL[dt], c[dt], 0, 0, 0); \
                c[dt] = __builtin_amdgcn_mfma_f32_16x16x32_bf16(alo, CURH[dt], c[dt], 0, 0, 0); \
            }                                                             \
        } while (0)

        PROJ_STEP(0, wh0, wl0, wh1, wl1, 1);
        PROJ_STEP(1, wh1, wl1, wh0, wl0, 2);
        PROJ_STEP(2, wh0, wl0, wh1, wl1, 3);
        PROJ_STEP(3, wh1, wl1, wh0, wl0, 3);
#undef PROJ_STEP
#undef LOADW

        // s = h . a
        float av[4];
#pragma unroll
        for (int dt = 0; dt < 4; ++dt) av[dt] = AK[h * CD + dt * 16 + row_l];
        float sacc[4];
#pragma unroll
        for (int r = 0; r < 4; ++r)
            sacc[r] = c[0][r] * av[0] + c[1][r] * av[1] + c[2][r] * av[2] + c[3][r] * av[3];
#pragma unroll
        for (int off = 1; off <= 8; off <<= 1)
#pragma unroll
            for (int r = 0; r < 4; ++r) sacc[r] += __shfl_xor(sacc[r], off, 64);

        float mx = fmaxf(fmaxf(sacc[0], sacc[1]), fmaxf(sacc[2], sacc[3]));
        mx = fmaxf(mx, __shfl_xor(mx, 16, 64));
        mx = fmaxf(mx, __shfl_xor(mx, 32, 64));
        if (l == 0) atomicMax(&smax_u[h * CB + b], fmap(mx));

        if (row_l == 0) {
#pragma unroll
            for (int r = 0; r < 4; ++r) {
                size_t si = (size_t)(h * CB + b) * CN + n0 + jg * 4 + r;
                s_ws[si] = sacc[r];
                e_ws[si] = __expf(sacc[r]);
            }
        }

#pragma unroll
        for (int dt = 0; dt < 4; ++dt)
#pragma unroll
            for (int r = 0; r < 4; ++r) tr[w][dt * 16 + row_l][jg * 4 + r] = c[dt][r];
    }
    __syncthreads();
    if (w < 8) {
        int h = w & 3, tt = w >> 2;
        int ntile = (i0 >> 4) + tt;
        int jc = l >> 5, d0 = l & 31;
        short8* hTs = reinterpret_cast<short8*>(hT);
#pragma unroll
        for (int half = 0; half < 2; ++half) {
            short8 pk;
#pragma unroll
            for (int e = 0; e < 8; ++e)
                pk[e] = (short)bf16bits(tr[w][half * 32 + d0][jc * 8 + e]);
            hTs[((size_t)(h * CB + b) * 256 + ntile * 2 + jc) * 64 + half * 32 + d0] = pk;
        }
    }
    __threadfence();
    gg.sync();

    // ================= phase 2: flash PV + head-mean + leaky ==============
    int hq = w >> 2, jq = w & 3;

    for (int idx = t; idx < CH * CN; idx += 1024) {
        int hh = idx >> 11, j = idx & 2047;
        e_sl[hh][j] = e_ws[(size_t)(hh * CB + b) * CN + j];
    }
    for (int idx = t; idx < IT * 64; idx += 1024) {
        int r = idx >> 6, wd = idx & 63;
        m_lds[r][wd] = mask_ws[(size_t)(i0 + r) * 64 + wd];
    }
    __syncthreads();

    float smax = funmap(smax_u[hq * CB + b]);
    float si0 = s_ws[(size_t)(hq * CB + b) * CN + i0 + row_l];
    float si1 = s_ws[(size_t)(hq * CB + b) * CN + i0 + 16 + row_l];
    float m0 = fmaxf(si0 + smax, 0.f), m1 = fmaxf(si1 + smax, 0.f);
    float Ei0 = __expf(si0 - m0), Ci0 = __expf(-m0);
    float Ei1 = __expf(si1 - m1), Ci1 = __expf(-m1);

    f32x4 c0[4], c1[4], cl0, cl1;
    f32x4 zero = {0.f, 0.f, 0.f, 0.f};
#pragma unroll
    for (int dt = 0; dt < 4; ++dt) { c0[dt] = zero; c1[dt] = zero; }
    cl0 = zero; cl1 = zero;

    short8 ones;
#pragma unroll
    for (int e = 0; e < 8; ++e) ones[e] = (short)0x3F80;  // bf16 1.0

    const short8* hp = reinterpret_cast<const short8*>(hT) +
                       ((size_t)(hq * CB + b) * 256 + jq * 64 + jg) * 64 + row_l;

    short8 bfA[4], bfB[4];
#pragma unroll
    for (int dt = 0; dt < 4; ++dt) bfA[dt] = hp[dt * 16];

#define ATTN_STEP(KK, BCUR, BNXT, KNXT)                                          \
    do {                                                                         \
        _Pragma("unroll") for (int dt = 0; dt < 4; ++dt)                         \
            BNXT[dt] = hp[(KNXT) * 256 + dt * 16];                               \
        int jl = jq * 512 + (KK) * 32 + jg * 8;                                  \
        f32x4 ej0 = *reinterpret_cast<const f32x4*>(&e_sl[hq][jl]);              \
        f32x4 ej1 = *reinterpret_cast<const f32x4*>(&e_sl[hq][jl + 4]);          \
        u32 by0 = m_lds[row_l][jq * 16 + (KK)] >> (jg * 8);                      \
        u32 by1 = m_lds[16 + row_l][jq * 16 + (KK)] >> (jg * 8);                 \
        short8 af0, af1;                                                         \
        _Pragma("unroll") for (int e = 0; e < 8; ++e) {                          \
            float ejv = (e < 4) ? ej0[e] : ej1[e - 4];                           \
            float w0 = ((by0 >> e) & 1u) ? fmaxf(Ei0 * ejv, Ci0) : 0.f;          \
            float w1 = ((by1 >> e) & 1u) ? fmaxf(Ei1 * ejv, Ci1) : 0.f;          \
            af0[e] = (short)bf16bits(w0);                                        \
            af1[e] = (short)bf16bits(w1);                                        \
        }                                                                        \
        _Pragma("unroll") for (int dt = 0; dt < 4; ++dt) {                       \
            c0[dt] = __builtin_amdgcn_mfma_f32_16x16x32_bf16(af0, BCUR[dt], c0[dt], 0, 0, 0); \
            c1[dt] = __builtin_amdgcn_mfma_f32_16x16x32_bf16(af1, BCUR[dt], c1[dt], 0, 0, 0); \
        }                                                                        \
        cl0 = __builtin_amdgcn_mfma_f32_16x16x32_bf16(af0, ones, cl0, 0, 0, 0);  \
        cl1 = __builtin_amdgcn_mfma_f32_16x16x32_bf16(af1, ones, cl1, 0, 0, 0);  \
    } while (0)

#pragma unroll
    for (int kp = 0; kp < 8; ++kp) {
        ATTN_STEP(2 * kp, bfA, bfB, 2 * kp + 1);
        ATTN_STEP(2 * kp + 1, bfB, bfA, (2 * kp + 2 < 16) ? 2 * kp + 2 : 15);
    }
#undef ATTN_STEP

    // cross-wave reduction over K-quarters (2 LDS slots)
    int slot = jq & 1;
    if (row_l == 0)
#pragma unroll
        for (int r = 0; r < 4; ++r) {
            lbuf[hq][jq][jg * 4 + r] = cl0[r];
            lbuf[hq][jq][16 + jg * 4 + r] = cl1[r];
        }
    if (jq < 2) {
#pragma unroll
        for (int dt = 0; dt < 4; ++dt)
#pragma unroll
            for (int r = 0; r < 4; ++r) {
                cbuf[hq][slot][jg * 4 + r][dt * 16 + row_l] = c0[dt][r];
                cbuf[hq][slot][16 + jg * 4 + r][dt * 16 + row_l] = c1[dt][r];
            }
    }
    __syncthreads();
    if (jq >= 2) {
#pragma unroll
        for (int dt = 0; dt < 4; ++dt)
#pragma unroll
            for (int r = 0; r < 4; ++r) {
                cbuf[hq][slot][jg * 4 + r][dt * 16 + row_l] += c0[dt][r];
                cbuf[hq][slot][16 + jg * 4 + r][dt * 16 + row_l] += c1[dt][r];
            }
    }
    __syncthreads();

    // epilogue
    for (int idx = t; idx < IT * CD; idx += 1024) {
        int row = idx >> 6, d = idx & 63;
        float acc = 0.f;
#pragma unroll
        for (int h = 0; h < CH; ++h) {
            float num = cbuf[h][0][row][d] + cbuf[h][1][row][d];
            float den = lbuf[h][0][row] + lbuf[h][1][row] + lbuf[h][2][row] + lbuf[h][3][row];
            acc += num / fmaxf(den, 1e-30f);
        }
        float o = acc * 0.25f;
        out[((size_t)b * CN + i0 + row) * CD + d] = o > 0.f ? o : 0.2f * o;
    }
}

// ---------------------------------------------------------------------------
extern "C" void kernel_launch(void* const* d_in, const int* in_sizes, int n_in,
                              void* d_out, int out_size, void* d_ws, size_t ws_size,
                              hipStream_t stream) {
    const float* X  = (const float*)d_in[0];   // [B,N,F]
    const int*   A  = (const int*)d_in[1];     // [N,N]
    const float* W  = (const float*)d_in[2];   // [H,F,D]
    const float* AK = (const float*)d_in[3];   // [H,D]
    float* out = (float*)d_out;                // [B,N,D]

    char* wp = (char*)d_ws;
    float* s_ws = (float*)wp;    wp += 131072;     // 16*2048 f32
    float* e_ws = (float*)wp;    wp += 131072;     // 16*2048 f32
    u32* smax_ws = (u32*)wp;     wp += 256;
    u32* mask_ws = (u32*)wp;     wp += 524288;     // 2048*64 u32
    u16* hT = (u16*)wp;          wp += 4194304;    // 16*256*64 short8 units
    u16* WThi = (u16*)wp;        wp += 65536;      // 4*64*128 bf16
    u16* WTlo = (u16*)wp;        wp += 65536;

    void* args[] = {(void*)&X, (void*)&A, (void*)&W, (void*)&AK, (void*)&out,
                    (void*)&s_ws, (void*)&e_ws, (void*)&smax_ws, (void*)&mask_ws,
                    (void*)&hT, (void*)&WThi, (void*)&WTlo};
    hipLaunchCooperativeKernel((const void*)fused_k, dim3(256), dim3(1024),
                               args, 0, stream);
}

// Round 9
// 61.797 us; speedup vs baseline: 4.7711x; 4.7711x over previous
//
#include <hip/hip_runtime.h>
#include <hip/hip_bf16.h>

typedef __attribute__((ext_vector_type(8))) short short8;
typedef __attribute__((ext_vector_type(4))) float f32x4;
typedef unsigned short u16;
typedef unsigned int u32;

constexpr int CB = 4, CN = 2048, CF = 128, CD = 64, CH = 4;
constexpr int IT = 32;   // i-rows per attn block

__device__ inline u32 fmap(float f) {
    u32 b = __float_as_uint(f);
    return b ^ ((u32)(((int)b) >> 31) | 0x80000000u);
}
__device__ inline float funmap(u32 u) {
    u32 b = (u & 0x80000000u) ? (u ^ 0x80000000u) : ~u;
    return __uint_as_float(b);
}
__device__ inline u16 bf16bits(float v) {
    __hip_bfloat16 b = __float2bfloat16(v);
    return *reinterpret_cast<u16*>(&b);
}

// ---------------------------------------------------------------------------
// Kernel 0: fused prep.
// Blocks [0,16384): pack adjacency -> bitmask (+ init smax).
// Blocks [16384,16512): W [H][F][D] f32 -> WT hi/lo bf16 in FRAGMENT-MAJOR
// layout: u16 index = (((h*4+kk)*4+dt)*64 + l)*8 + e, where the (l,e) element
// is W[f = kk*32 + (l>>4)*8 + e][d = dt*16 + (l&15)]. proj's B-frag loads
// become unit[(h*16+kk*4+dt)*64 + l] -> one coalesced 1KB txn per instr.
// ---------------------------------------------------------------------------
__global__ __launch_bounds__(256) void prep_k(const int* __restrict__ A,
                                              const float* __restrict__ W,
                                              u32* __restrict__ mask,
                                              u32* __restrict__ smax_u,
                                              u16* __restrict__ WThi,
                                              u16* __restrict__ WTlo) {
    int blk = blockIdx.x, t = threadIdx.x;
    if (blk < 16384) {
        int gid = blk * 256 + t;
        if (blk == 0 && t < CH * CB) smax_u[t] = 0u;  // ~ -inf under fmap
        unsigned long long mk = __ballot(A[gid] > 0);
        if ((t & 63) == 0) {
            mask[gid >> 5] = (u32)mk;
            mask[(gid >> 5) + 1] = (u32)(mk >> 32);
        }
    } else {
        int idx = (blk - 16384) * 256 + t;   // 0..32767
        int e = idx & 7;
        int l = (idx >> 3) & 63;
        int dt = (idx >> 9) & 3;
        int kk = (idx >> 11) & 3;
        int h = idx >> 13;
        int f = kk * 32 + (l >> 4) * 8 + e;
        int d = dt * 16 + (l & 15);
        float v = W[(h * CF + f) * CD + d];
        __hip_bfloat16 bh = __float2bfloat16(v);
        WThi[idx] = *reinterpret_cast<u16*>(&bh);
        WTlo[idx] = bf16bits(v - __bfloat162float(bh));
    }
}

// ---------------------------------------------------------------------------
// Kernel 1: MFMA projection, fully load-hoisted, coalesced WT loads.
// wave = head; block = 16-row tile. Split-bf16: Xhi*Whi + Xhi*Wlo + Xlo*Whi.
// hT layout: 16B unit = 8 consecutive j at fixed d: unit[(hb*256 + jc)*64 + d]
// ---------------------------------------------------------------------------
__global__ __launch_bounds__(256, 2) void proj_k(const float* __restrict__ X,
                                                 const u16* __restrict__ WThi,
                                                 const u16* __restrict__ WTlo,
                                                 const float* __restrict__ AK,
                                                 u16* __restrict__ hT,
                                                 float* __restrict__ sout,
                                                 float* __restrict__ eout,
                                                 u32* __restrict__ smax_u) {
    __shared__ float tr[4][CD][17];   // per-wave transpose staging (17.4 KB)

    int blk = blockIdx.x;             // b*128 + ntile
    int ntile = blk & 127;
    int b = blk >> 7;
    int n0 = ntile * 16;
    int t = threadIdx.x;
    int w = t >> 6, l = t & 63;
    int h = w;
    int row_l = l & 15, jg = l >> 4;

    const float* xrow = X + ((size_t)b * CN + n0 + row_l) * CF + jg * 8;
    const short8* whiU = reinterpret_cast<const short8*>(WThi) + (size_t)h * 1024 + l;
    const short8* wloU = reinterpret_cast<const short8*>(WTlo) + (size_t)h * 1024 + l;

    // ---- hoist ALL loads (8 X float4 + 32 coalesced WT short8) ----
    float4 xa[4], xb[4];
#pragma unroll
    for (int kk = 0; kk < 4; ++kk) {
        xa[kk] = *reinterpret_cast<const float4*>(xrow + kk * 32);
        xb[kk] = *reinterpret_cast<const float4*>(xrow + kk * 32 + 4);
    }
    short8 bhi[4][4], blo[4][4];
#pragma unroll
    for (int kk = 0; kk < 4; ++kk)
#pragma unroll
        for (int dt = 0; dt < 4; ++dt) {
            bhi[kk][dt] = whiU[(kk * 4 + dt) * 64];
            blo[kk][dt] = wloU[(kk * 4 + dt) * 64];
        }

    f32x4 c[4];
    f32x4 zero = {0.f, 0.f, 0.f, 0.f};
#pragma unroll
    for (int dt = 0; dt < 4; ++dt) c[dt] = zero;

#pragma unroll
    for (int kk = 0; kk < 4; ++kk) {
        float xv[8] = {xa[kk].x, xa[kk].y, xa[kk].z, xa[kk].w,
                       xb[kk].x, xb[kk].y, xb[kk].z, xb[kk].w};
        short8 ahi, alo;
#pragma unroll
        for (int e = 0; e < 8; ++e) {
            __hip_bfloat16 bh = __float2bfloat16(xv[e]);
            ahi[e] = (short)*reinterpret_cast<u16*>(&bh);
            alo[e] = (short)bf16bits(xv[e] - __bfloat162float(bh));
        }
#pragma unroll
        for (int dt = 0; dt < 4; ++dt) {
            c[dt] = __builtin_amdgcn_mfma_f32_16x16x32_bf16(ahi, bhi[kk][dt], c[dt], 0, 0, 0);
            c[dt] = __builtin_amdgcn_mfma_f32_16x16x32_bf16(ahi, blo[kk][dt], c[dt], 0, 0, 0);
            c[dt] = __builtin_amdgcn_mfma_f32_16x16x32_bf16(alo, bhi[kk][dt], c[dt], 0, 0, 0);
        }
    }

    // ---- s = h . a ----
    float av[4];
#pragma unroll
    for (int dt = 0; dt < 4; ++dt) av[dt] = AK[h * CD + dt * 16 + row_l];
    float sacc[4];
#pragma unroll
    for (int r = 0; r < 4; ++r)
        sacc[r] = c[0][r] * av[0] + c[1][r] * av[1] + c[2][r] * av[2] + c[3][r] * av[3];
#pragma unroll
    for (int off = 1; off <= 8; off <<= 1)
#pragma unroll
        for (int r = 0; r < 4; ++r) sacc[r] += __shfl_xor(sacc[r], off, 64);

    float mx = fmaxf(fmaxf(sacc[0], sacc[1]), fmaxf(sacc[2], sacc[3]));
    mx = fmaxf(mx, __shfl_xor(mx, 16, 64));
    mx = fmaxf(mx, __shfl_xor(mx, 32, 64));
    if (l == 0) atomicMax(&smax_u[h * CB + b], fmap(mx));

    if (row_l == 0) {
#pragma unroll
        for (int r = 0; r < 4; ++r) {
            size_t si = (size_t)(h * CB + b) * CN + n0 + jg * 4 + r;
            sout[si] = sacc[r];
            eout[si] = __expf(sacc[r]);
        }
    }

    // ---- transpose to hT layout via LDS; coalesced 16B stores ----
#pragma unroll
    for (int dt = 0; dt < 4; ++dt)
#pragma unroll
        for (int r = 0; r < 4; ++r) tr[w][dt * 16 + row_l][jg * 4 + r] = c[dt][r];
    __syncthreads();

    short8* hTs = reinterpret_cast<short8*>(hT);
    int jc = l >> 5, d0 = l & 31;
#pragma unroll
    for (int half = 0; half < 2; ++half) {
        short8 pk;
#pragma unroll
        for (int e = 0; e < 8; ++e)
            pk[e] = (short)bf16bits(tr[w][half * 32 + d0][jc * 8 + e]);
        hTs[((size_t)(h * CB + b) * 256 + ntile * 2 + jc) * 64 + half * 32 + d0] = pk;
    }
}

// ---------------------------------------------------------------------------
// Kernel 2: fused flash PV + head-mean + leaky. 1024 thr = 16 waves =
// (head hq, K-quarter jq of 512). Grid 256, XCD-swizzled (2 XCDs per b).
// K-loop is a REAL loop (#pragma unroll 1, 2 steps/iter) so the body stays
// I-cache-resident; depth-1 B-frag prefetch via named bfA/bfB; s_setprio
// around the MFMA clusters. Weight w = mask ? max(Ei*Ej, Ci) : 0;
// denominator = ones-MFMA of the SAME bf16-rounded A-frag.
// ---------------------------------------------------------------------------
__global__ __launch_bounds__(1024, 4) void attn_k(const u16* __restrict__ hT,
                                                  const float* __restrict__ s_ws,
                                                  const float* __restrict__ e_ws,
                                                  const u32* __restrict__ smax_u,
                                                  const u32* __restrict__ mask32,
                                                  float* __restrict__ out) {
    __shared__ alignas(16) float e_sl[CH][CN];   // 32 KB
    __shared__ u32 m_lds[IT][65];                // 8.3 KB
    __shared__ float cbuf[CH][2][IT][68];        // 69.6 KB
    __shared__ float lbuf[CH][4][IT];            // 2 KB

    int orig = blockIdx.x;
    int xcd = orig & 7, pos = orig >> 3;   // round-robin XCD assignment
    int b = xcd >> 1;                      // 2 XCDs per b
    int it = (xcd & 1) * 32 + pos;         // tile 0..63
    int i0 = it * IT;
    int t = threadIdx.x, w = t >> 6, l = t & 63;
    int hq = w >> 2, jq = w & 3;
    int row_l = l & 15, jg = l >> 4;

    for (int idx = t; idx < CH * CN; idx += 1024) {
        int hh = idx >> 11, j = idx & 2047;
        e_sl[hh][j] = e_ws[(size_t)(hh * CB + b) * CN + j];
    }
    for (int idx = t; idx < IT * 64; idx += 1024) {
        int r = idx >> 6, wd = idx & 63;
        m_lds[r][wd] = mask32[(size_t)(i0 + r) * 64 + wd];
    }
    __syncthreads();

    float smax = funmap(smax_u[hq * CB + b]);
    float si0 = s_ws[(size_t)(hq * CB + b) * CN + i0 + row_l];
    float si1 = s_ws[(size_t)(hq * CB + b) * CN + i0 + 16 + row_l];
    float m0 = fmaxf(si0 + smax, 0.f), m1 = fmaxf(si1 + smax, 0.f);
    float Ei0 = __expf(si0 - m0), Ci0 = __expf(-m0);
    float Ei1 = __expf(si1 - m1), Ci1 = __expf(-m1);

    f32x4 c0[4], c1[4], cl0, cl1;
    f32x4 zero = {0.f, 0.f, 0.f, 0.f};
#pragma unroll
    for (int dt = 0; dt < 4; ++dt) { c0[dt] = zero; c1[dt] = zero; }
    cl0 = zero; cl1 = zero;

    short8 ones;
#pragma unroll
    for (int e = 0; e < 8; ++e) ones[e] = (short)0x3F80;  // bf16 1.0

    // B pointer: unit[(hb*256 + jq*64 + kk*4 + jg)*64 + dt*16 + row_l]
    const short8* hp = reinterpret_cast<const short8*>(hT) +
                       ((size_t)(hq * CB + b) * 256 + jq * 64 + jg) * 64 + row_l;

    short8 bfA[4], bfB[4];
#pragma unroll
    for (int dt = 0; dt < 4; ++dt) bfA[dt] = hp[dt * 16];

#define ATTN_STEP(KK, BCUR, BNXT, KNXT)                                          \
    do {                                                                         \
        _Pragma("unroll") for (int dt = 0; dt < 4; ++dt)                         \
            BNXT[dt] = hp[(KNXT) * 256 + dt * 16];                               \
        int jl = jq * 512 + (KK) * 32 + jg * 8;                                  \
        f32x4 ej0 = *reinterpret_cast<const f32x4*>(&e_sl[hq][jl]);              \
        f32x4 ej1 = *reinterpret_cast<const f32x4*>(&e_sl[hq][jl + 4]);          \
        u32 by0 = m_lds[row_l][jq * 16 + (KK)] >> (jg * 8);                      \
        u32 by1 = m_lds[16 + row_l][jq * 16 + (KK)] >> (jg * 8);                 \
        short8 af0, af1;                                                         \
        _Pragma("unroll") for (int e = 0; e < 8; ++e) {                          \
            float ejv = (e < 4) ? ej0[e] : ej1[e - 4];                           \
            float w0 = ((by0 >> e) & 1u) ? fmaxf(Ei0 * ejv, Ci0) : 0.f;          \
            float w1 = ((by1 >> e) & 1u) ? fmaxf(Ei1 * ejv, Ci1) : 0.f;          \
            af0[e] = (short)bf16bits(w0);                                        \
            af1[e] = (short)bf16bits(w1);                                        \
        }                                                                        \
        __builtin_amdgcn_s_setprio(1);                                           \
        _Pragma("unroll") for (int dt = 0; dt < 4; ++dt) {                       \
            c0[dt] = __builtin_amdgcn_mfma_f32_16x16x32_bf16(af0, BCUR[dt], c0[dt], 0, 0, 0); \
            c1[dt] = __builtin_amdgcn_mfma_f32_16x16x32_bf16(af1, BCUR[dt], c1[dt], 0, 0, 0); \
        }                                                                        \
        cl0 = __builtin_amdgcn_mfma_f32_16x16x32_bf16(af0, ones, cl0, 0, 0, 0);  \
        cl1 = __builtin_amdgcn_mfma_f32_16x16x32_bf16(af1, ones, cl1, 0, 0, 0);  \
        __builtin_amdgcn_s_setprio(0);                                           \
    } while (0)

#pragma unroll 1
    for (int kp = 0; kp < 16; kp += 2) {
        ATTN_STEP(kp, bfA, bfB, kp + 1);
        int kn = (kp + 2 < 16) ? kp + 2 : 15;
        ATTN_STEP(kp + 1, bfB, bfA, kn);
    }
#undef ATTN_STEP

    // cross-wave reduction over K-quarters (2 LDS slots)
    int slot = jq & 1;
    if (row_l == 0)
#pragma unroll
        for (int r = 0; r < 4; ++r) {
            lbuf[hq][jq][jg * 4 + r] = cl0[r];
            lbuf[hq][jq][16 + jg * 4 + r] = cl1[r];
        }
    if (jq < 2) {
#pragma unroll
        for (int dt = 0; dt < 4; ++dt)
#pragma unroll
            for (int r = 0; r < 4; ++r) {
                cbuf[hq][slot][jg * 4 + r][dt * 16 + row_l] = c0[dt][r];
                cbuf[hq][slot][16 + jg * 4 + r][dt * 16 + row_l] = c1[dt][r];
            }
    }
    __syncthreads();
    if (jq >= 2) {
#pragma unroll
        for (int dt = 0; dt < 4; ++dt)
#pragma unroll
            for (int r = 0; r < 4; ++r) {
                cbuf[hq][slot][jg * 4 + r][dt * 16 + row_l] += c0[dt][r];
                cbuf[hq][slot][16 + jg * 4 + r][dt * 16 + row_l] += c1[dt][r];
            }
    }
    __syncthreads();

    // epilogue: slot-sum, divide, head-mean, leaky, store
    for (int idx = t; idx < IT * CD; idx += 1024) {
        int row = idx >> 6, d = idx & 63;
        float acc = 0.f;
#pragma unroll
        for (int h = 0; h < CH; ++h) {
            float num = cbuf[h][0][row][d] + cbuf[h][1][row][d];
            float den = lbuf[h][0][row] + lbuf[h][1][row] + lbuf[h][2][row] + lbuf[h][3][row];
            acc += num / fmaxf(den, 1e-30f);
        }
        float o = acc * 0.25f;
        out[((size_t)b * CN + i0 + row) * CD + d] = o > 0.f ? o : 0.2f * o;
    }
}

// ---------------------------------------------------------------------------
extern "C" void kernel_launch(void* const* d_in, const int* in_sizes, int n_in,
                              void* d_out, int out_size, void* d_ws, size_t ws_size,
                              hipStream_t stream) {
    const float* X  = (const float*)d_in[0];   // [B,N,F]
    const int*   A  = (const int*)d_in[1];     // [N,N]
    const float* W  = (const float*)d_in[2];   // [H,F,D]
    const float* AK = (const float*)d_in[3];   // [H,D]
    float* out = (float*)d_out;                // [B,N,D]

    char* wp = (char*)d_ws;
    float* s_ws = (float*)wp;    wp += 131072;     // 16*2048 f32
    float* e_ws = (float*)wp;    wp += 131072;     // 16*2048 f32
    u32* smax_ws = (u32*)wp;     wp += 256;
    u32* mask_ws = (u32*)wp;     wp += 524288;     // 2048*64 u32
    u16* hT = (u16*)wp;          wp += 4194304;    // 16*256*64 short8 units
    u16* WThi = (u16*)wp;        wp += 65536;      // fragment-major bf16
    u16* WTlo = (u16*)wp;        wp += 65536;

    prep_k<<<16384 + 128, 256, 0, stream>>>(A, W, mask_ws, smax_ws, WThi, WTlo);
    proj_k<<<CB * (CN / 16), 256, 0, stream>>>(X, WThi, WTlo, AK, hT, s_ws, e_ws, smax_ws);
    attn_k<<<CB * (CN / IT), 1024, 0, stream>>>(hT, s_ws, e_ws, smax_ws, mask_ws, out);
}

// Round 11
// 59.403 us; speedup vs baseline: 4.9634x; 1.0403x over previous
//
#include <hip/hip_runtime.h>
#include <hip/hip_bf16.h>
#include <hip/hip_fp16.h>

typedef __attribute__((ext_vector_type(8))) short short8;
typedef __attribute__((ext_vector_type(8))) _Float16 f16x8;
typedef __attribute__((ext_vector_type(2))) _Float16 f16x2;
typedef __attribute__((ext_vector_type(4))) float f32x4;
typedef __attribute__((ext_vector_type(4))) unsigned int u32x4;
typedef unsigned short u16;
typedef unsigned int u32;

constexpr int CB = 4, CN = 2048, CF = 128, CD = 64, CH = 4;
constexpr int IT = 32;   // i-rows per attn block

__device__ inline u32 fmap(float f) {
    u32 b = __float_as_uint(f);
    return b ^ ((u32)(((int)b) >> 31) | 0x80000000u);
}
__device__ inline float funmap(u32 u) {
    u32 b = (u & 0x80000000u) ? (u ^ 0x80000000u) : ~u;
    return __uint_as_float(b);
}
__device__ inline u16 bf16bits(float v) {
    __hip_bfloat16 b = __float2bfloat16(v);
    return *reinterpret_cast<u16*>(&b);
}

// ---------------------------------------------------------------------------
// Kernel 0: fused prep.
// Blocks [0,16384): pack adjacency -> bitmask (+ init smax).
// Blocks [16384,16512): W [H][F][D] f32 -> WT hi/lo bf16 fragment-major:
// u16 idx = (((h*4+kk)*4+dt)*64 + l)*8 + e  <->  W[f=kk*32+(l>>4)*8+e][d=dt*16+(l&15)]
// ---------------------------------------------------------------------------
__global__ __launch_bounds__(256) void prep_k(const int* __restrict__ A,
                                              const float* __restrict__ W,
                                              u32* __restrict__ mask,
                                              u32* __restrict__ smax_u,
                                              u16* __restrict__ WThi,
                                              u16* __restrict__ WTlo) {
    int blk = blockIdx.x, t = threadIdx.x;
    if (blk < 16384) {
        int gid = blk * 256 + t;
        if (blk == 0 && t < CH * CB) smax_u[t] = 0u;  // ~ -inf under fmap
        unsigned long long mk = __ballot(A[gid] > 0);
        if ((t & 63) == 0) {
            mask[gid >> 5] = (u32)mk;
            mask[(gid >> 5) + 1] = (u32)(mk >> 32);
        }
    } else {
        int idx = (blk - 16384) * 256 + t;   // 0..32767
        int e = idx & 7;
        int l = (idx >> 3) & 63;
        int dt = (idx >> 9) & 3;
        int kk = (idx >> 11) & 3;
        int h = idx >> 13;
        int f = kk * 32 + (l >> 4) * 8 + e;
        int d = dt * 16 + (l & 15);
        float v = W[(h * CF + f) * CD + d];
        __hip_bfloat16 bh = __float2bfloat16(v);
        WThi[idx] = *reinterpret_cast<u16*>(&bh);
        WTlo[idx] = bf16bits(v - __bfloat162float(bh));
    }
}

// ---------------------------------------------------------------------------
// Kernel 1: MFMA projection, load-hoisted, coalesced WT loads.
// wave = head; block = 16-row tile. Split-bf16: Xhi*Whi + Xhi*Wlo + Xlo*Whi.
// hT in F16: 16B unit = 8 consecutive j at fixed d: unit[(hb*256+jc)*64+d].
// E = exp(s) stored as f16.
// ---------------------------------------------------------------------------
__global__ __launch_bounds__(256, 2) void proj_k(const float* __restrict__ X,
                                                 const u16* __restrict__ WThi,
                                                 const u16* __restrict__ WTlo,
                                                 const float* __restrict__ AK,
                                                 u16* __restrict__ hT,
                                                 float* __restrict__ sout,
                                                 u16* __restrict__ eout,
                                                 u32* __restrict__ smax_u) {
    __shared__ float tr[4][CD][17];   // per-wave transpose staging (17.4 KB)

    int blk = blockIdx.x;             // b*128 + ntile
    int ntile = blk & 127;
    int b = blk >> 7;
    int n0 = ntile * 16;
    int t = threadIdx.x;
    int w = t >> 6, l = t & 63;
    int h = w;
    int row_l = l & 15, jg = l >> 4;

    const float* xrow = X + ((size_t)b * CN + n0 + row_l) * CF + jg * 8;
    const short8* whiU = reinterpret_cast<const short8*>(WThi) + (size_t)h * 1024 + l;
    const short8* wloU = reinterpret_cast<const short8*>(WTlo) + (size_t)h * 1024 + l;

    float4 xa[4], xb[4];
#pragma unroll
    for (int kk = 0; kk < 4; ++kk) {
        xa[kk] = *reinterpret_cast<const float4*>(xrow + kk * 32);
        xb[kk] = *reinterpret_cast<const float4*>(xrow + kk * 32 + 4);
    }
    short8 bhi[4][4], blo[4][4];
#pragma unroll
    for (int kk = 0; kk < 4; ++kk)
#pragma unroll
        for (int dt = 0; dt < 4; ++dt) {
            bhi[kk][dt] = whiU[(kk * 4 + dt) * 64];
            blo[kk][dt] = wloU[(kk * 4 + dt) * 64];
        }

    f32x4 c[4];
    f32x4 zero = {0.f, 0.f, 0.f, 0.f};
#pragma unroll
    for (int dt = 0; dt < 4; ++dt) c[dt] = zero;

#pragma unroll
    for (int kk = 0; kk < 4; ++kk) {
        float xv[8] = {xa[kk].x, xa[kk].y, xa[kk].z, xa[kk].w,
                       xb[kk].x, xb[kk].y, xb[kk].z, xb[kk].w};
        short8 ahi, alo;
#pragma unroll
        for (int e = 0; e < 8; ++e) {
            __hip_bfloat16 bh = __float2bfloat16(xv[e]);
            ahi[e] = (short)*reinterpret_cast<u16*>(&bh);
            alo[e] = (short)bf16bits(xv[e] - __bfloat162float(bh));
        }
#pragma unroll
        for (int dt = 0; dt < 4; ++dt) {
            c[dt] = __builtin_amdgcn_mfma_f32_16x16x32_bf16(ahi, bhi[kk][dt], c[dt], 0, 0, 0);
            c[dt] = __builtin_amdgcn_mfma_f32_16x16x32_bf16(ahi, blo[kk][dt], c[dt], 0, 0, 0);
            c[dt] = __builtin_amdgcn_mfma_f32_16x16x32_bf16(alo, bhi[kk][dt], c[dt], 0, 0, 0);
        }
    }

    // ---- s = h . a ----
    float av[4];
#pragma unroll
    for (int dt = 0; dt < 4; ++dt) av[dt] = AK[h * CD + dt * 16 + row_l];
    float sacc[4];
#pragma unroll
    for (int r = 0; r < 4; ++r)
        sacc[r] = c[0][r] * av[0] + c[1][r] * av[1] + c[2][r] * av[2] + c[3][r] * av[3];
#pragma unroll
    for (int off = 1; off <= 8; off <<= 1)
#pragma unroll
        for (int r = 0; r < 4; ++r) sacc[r] += __shfl_xor(sacc[r], off, 64);

    float mx = fmaxf(fmaxf(sacc[0], sacc[1]), fmaxf(sacc[2], sacc[3]));
    mx = fmaxf(mx, __shfl_xor(mx, 16, 64));
    mx = fmaxf(mx, __shfl_xor(mx, 32, 64));
    if (l == 0) atomicMax(&smax_u[h * CB + b], fmap(mx));

    if (row_l == 0) {
#pragma unroll
        for (int r = 0; r < 4; ++r) {
            size_t si = (size_t)(h * CB + b) * CN + n0 + jg * 4 + r;
            sout[si] = sacc[r];
            _Float16 ev = (_Float16)__expf(sacc[r]);
            eout[si] = *reinterpret_cast<u16*>(&ev);
        }
    }

    // ---- transpose to hT (f16) via LDS; coalesced 16B stores ----
#pragma unroll
    for (int dt = 0; dt < 4; ++dt)
#pragma unroll
        for (int r = 0; r < 4; ++r) tr[w][dt * 16 + row_l][jg * 4 + r] = c[dt][r];
    __syncthreads();

    f16x8* hTs = reinterpret_cast<f16x8*>(hT);
    int jc = l >> 5, d0 = l & 31;
#pragma unroll
    for (int half = 0; half < 2; ++half) {
        f16x8 pk;
#pragma unroll
        for (int e = 0; e < 8; ++e)
            pk[e] = (_Float16)tr[w][half * 32 + d0][jc * 8 + e];
        hTs[((size_t)(h * CB + b) * 256 + ntile * 2 + jc) * 64 + half * 32 + d0] = pk;
    }
}

// ---------------------------------------------------------------------------
// Kernel 2: fused flash PV + head-mean + leaky, PACKED-F16 weight gen.
// 1024 thr = 16 waves = (head hq, K-quarter jq of 512). Grid 256, XCD-swizzle.
// Weight pair = max(Ei2*e2, Ci2) & maskword (v_pk_mul_f16 + v_pk_max_f16 via
// native _Float16 vectors) -> directly the f16 MFMA A-operand. Denominator =
// ones-MFMA of the SAME f16 weights. Depth-1 B prefetch, setprio, unroll-1.
// ---------------------------------------------------------------------------
__global__ __launch_bounds__(1024, 4) void attn_k(const u16* __restrict__ hT,
                                                  const float* __restrict__ s_ws,
                                                  const u32* __restrict__ e_ws32,
                                                  const u32* __restrict__ smax_u,
                                                  const u32* __restrict__ mask32,
                                                  float* __restrict__ out) {
    __shared__ u32 e_sl[CH][CN / 2];             // 16 KB (f16 pairs)
    __shared__ u32 m_lds[IT][65];                // 8.3 KB
    __shared__ float cbuf[CH][2][IT][68];        // 69.6 KB
    __shared__ float lbuf[CH][4][IT];            // 2 KB

    int orig = blockIdx.x;
    int xcd = orig & 7, pos = orig >> 3;   // round-robin XCD assignment
    int b = xcd >> 1;                      // 2 XCDs per b
    int it = (xcd & 1) * 32 + pos;         // tile 0..63
    int i0 = it * IT;
    int t = threadIdx.x, w = t >> 6, l = t & 63;
    int hq = w >> 2, jq = w & 3;
    int row_l = l & 15, jg = l >> 4;

    for (int idx = t; idx < CH * (CN / 2); idx += 1024) {
        int hh = idx >> 10, j = idx & 1023;
        e_sl[hh][j] = e_ws32[(size_t)(hh * CB + b) * (CN / 2) + j];
    }
    for (int idx = t; idx < IT * 64; idx += 1024) {
        int r = idx >> 6, wd = idx & 63;
        m_lds[r][wd] = mask32[(size_t)(i0 + r) * 64 + wd];
    }
    __syncthreads();

    float smax = funmap(smax_u[hq * CB + b]);
    float si0 = s_ws[(size_t)(hq * CB + b) * CN + i0 + row_l];
    float si1 = s_ws[(size_t)(hq * CB + b) * CN + i0 + 16 + row_l];
    float m0 = fmaxf(si0 + smax, 0.f), m1 = fmaxf(si1 + smax, 0.f);
    _Float16 ei0s = (_Float16)__expf(si0 - m0), ci0s = (_Float16)__expf(-m0);
    _Float16 ei1s = (_Float16)__expf(si1 - m1), ci1s = (_Float16)__expf(-m1);
    f16x2 Ei0 = {ei0s, ei0s}, Ci0 = {ci0s, ci0s};
    f16x2 Ei1 = {ei1s, ei1s}, Ci1 = {ci1s, ci1s};

    f32x4 c0[4], c1[4], cl0, cl1;
    f32x4 zero = {0.f, 0.f, 0.f, 0.f};
#pragma unroll
    for (int dt = 0; dt < 4; ++dt) { c0[dt] = zero; c1[dt] = zero; }
    cl0 = zero; cl1 = zero;

    f16x8 ones;
#pragma unroll
    for (int e = 0; e < 8; ++e) ones[e] = (_Float16)1.0f;

    // B pointer: unit[(hb*256 + jq*64 + kk*4 + jg)*64 + dt*16 + row_l]
    const f16x8* hp = reinterpret_cast<const f16x8*>(hT) +
                      ((size_t)(hq * CB + b) * 256 + jq * 64 + jg) * 64 + row_l;

    f16x8 bfA[4], bfB[4];
#pragma unroll
    for (int dt = 0; dt < 4; ++dt) bfA[dt] = hp[dt * 16];

#define ATTN_STEP(KK, BCUR, BNXT, KNXT)                                          \
    do {                                                                         \
        _Pragma("unroll") for (int dt = 0; dt < 4; ++dt)                         \
            BNXT[dt] = hp[(KNXT) * 256 + dt * 16];                               \
        int jw = jq * 256 + (KK) * 16 + jg * 4;                                  \
        u32x4 ejw = *reinterpret_cast<const u32x4*>(&e_sl[hq][jw]);              \
        u32 by0 = m_lds[row_l][jq * 16 + (KK)] >> (jg * 8);                      \
        u32 by1 = m_lds[16 + row_l][jq * 16 + (KK)] >> (jg * 8);                 \
        u32x4 af0w, af1w;                                                        \
        _Pragma("unroll") for (int p = 0; p < 4; ++p) {                          \
            u32 ewv = ejw[p];                                                    \
            f16x2 e2 = __builtin_bit_cast(f16x2, ewv);                           \
            f16x2 t0 = __builtin_elementwise_max(Ei0 * e2, Ci0);                 \
            f16x2 t1 = __builtin_elementwise_max(Ei1 * e2, Ci1);                 \
            u32 mk0 = (((by0 >> (2 * p)) & 1u) ? 0xFFFFu : 0u) |                 \
                      (((by0 >> (2 * p + 1)) & 1u) ? 0xFFFF0000u : 0u);          \
            u32 mk1 = (((by1 >> (2 * p)) & 1u) ? 0xFFFFu : 0u) |                 \
                      (((by1 >> (2 * p + 1)) & 1u) ? 0xFFFF0000u : 0u);          \
            af0w[p] = __builtin_bit_cast(u32, t0) & mk0;                         \
            af1w[p] = __builtin_bit_cast(u32, t1) & mk1;                         \
        }                                                                        \
        f16x8 af0 = __builtin_bit_cast(f16x8, af0w);                             \
        f16x8 af1 = __builtin_bit_cast(f16x8, af1w);                             \
        __builtin_amdgcn_s_setprio(1);                                           \
        _Pragma("unroll") for (int dt = 0; dt < 4; ++dt) {                       \
            c0[dt] = __builtin_amdgcn_mfma_f32_16x16x32_f16(af0, BCUR[dt], c0[dt], 0, 0, 0); \
            c1[dt] = __builtin_amdgcn_mfma_f32_16x16x32_f16(af1, BCUR[dt], c1[dt], 0, 0, 0); \
        }                                                                        \
        cl0 = __builtin_amdgcn_mfma_f32_16x16x32_f16(af0, ones, cl0, 0, 0, 0);   \
        cl1 = __builtin_amdgcn_mfma_f32_16x16x32_f16(af1, ones, cl1, 0, 0, 0);   \
        __builtin_amdgcn_s_setprio(0);                                           \
    } while (0)

#pragma unroll 1
    for (int kp = 0; kp < 16; kp += 2) {
        ATTN_STEP(kp, bfA, bfB, kp + 1);
        int kn = (kp + 2 < 16) ? kp + 2 : 15;
        ATTN_STEP(kp + 1, bfB, bfA, kn);
    }
#undef ATTN_STEP

    // cross-wave reduction over K-quarters (2 LDS slots)
    // C/D layout: col = lane&15, row = (lane>>4)*4 + reg
    int slot = jq & 1;
    if (row_l == 0)
#pragma unroll
        for (int r = 0; r < 4; ++r) {
            lbuf[hq][jq][jg * 4 + r] = cl0[r];
            lbuf[hq][jq][16 + jg * 4 + r] = cl1[r];
        }
    if (jq < 2) {
#pragma unroll
        for (int dt = 0; dt < 4; ++dt)
#pragma unroll
            for (int r = 0; r < 4; ++r) {
                cbuf[hq][slot][jg * 4 + r][dt * 16 + row_l] = c0[dt][r];
                cbuf[hq][slot][16 + jg * 4 + r][dt * 16 + row_l] = c1[dt][r];
            }
    }
    __syncthreads();
    if (jq >= 2) {
#pragma unroll
        for (int dt = 0; dt < 4; ++dt)
#pragma unroll
            for (int r = 0; r < 4; ++r) {
                cbuf[hq][slot][jg * 4 + r][dt * 16 + row_l] += c0[dt][r];
                cbuf[hq][slot][16 + jg * 4 + r][dt * 16 + row_l] += c1[dt][r];
            }
    }
    __syncthreads();

    // epilogue: slot-sum, divide, head-mean, leaky, store
    for (int idx = t; idx < IT * CD; idx += 1024) {
        int row = idx >> 6, d = idx & 63;
        float acc = 0.f;
#pragma unroll
        for (int h = 0; h < CH; ++h) {
            float num = cbuf[h][0][row][d] + cbuf[h][1][row][d];
            float den = lbuf[h][0][row] + lbuf[h][1][row] + lbuf[h][2][row] + lbuf[h][3][row];
            acc += num / fmaxf(den, 1e-30f);
        }
        float o = acc * 0.25f;
        out[((size_t)b * CN + i0 + row) * CD + d] = o > 0.f ? o : 0.2f * o;
    }
}

// ---------------------------------------------------------------------------
extern "C" void kernel_launch(void* const* d_in, const int* in_sizes, int n_in,
                              void* d_out, int out_size, void* d_ws, size_t ws_size,
                              hipStream_t stream) {
    const float* X  = (const float*)d_in[0];   // [B,N,F]
    const int*   A  = (const int*)d_in[1];     // [N,N]
    const float* W  = (const float*)d_in[2];   // [H,F,D]
    const float* AK = (const float*)d_in[3];   // [H,D]
    float* out = (float*)d_out;                // [B,N,D]

    char* wp = (char*)d_ws;
    float* s_ws = (float*)wp;    wp += 131072;     // 16*2048 f32
    u16* e_ws = (u16*)wp;        wp += 131072;     // 16*2048 f16 (64KB used)
    u32* smax_ws = (u32*)wp;     wp += 256;
    u32* mask_ws = (u32*)wp;     wp += 524288;     // 2048*64 u32
    u16* hT = (u16*)wp;          wp += 4194304;    // 16*256*64 f16x8 units
    u16* WThi = (u16*)wp;        wp += 65536;      // fragment-major bf16
    u16* WTlo = (u16*)wp;        wp += 65536;

    prep_k<<<16384 + 128, 256, 0, stream>>>(A, W, mask_ws, smax_ws, WThi, WTlo);
    proj_k<<<CB * (CN / 16), 256, 0, stream>>>(X, WThi, WTlo, AK, hT, s_ws, e_ws, smax_ws);
    attn_k<<<CB * (CN / IT), 1024, 0, stream>>>(hT, s_ws, (const u32*)e_ws,
                                                smax_ws, mask_ws, out);
}